// Round 1
// baseline (460.007 us; speedup 1.0000x reference)
//
#include <hip/hip_runtime.h>
#include <math.h>

#define NODE_IN 64
#define NODE_OUT 96
#define EDGE_IN 16
#define EDGE_OUT 64
#define ACC_W 80          // NODE_IN + EDGE_IN
#define NB 500            // graphs
#define FPD 2048
#define FPE 128
#define XDIM 288          // 160 + 128
#define BN_EPS 1e-5f

// ---------------- Kernel 1: per-edge scatter of raw features into per-block
// LDS accumulators [500][80] (+ per-graph edge count), flushed to partials. ----
__global__ __launch_bounds__(1024) void edge_scatter(
    const float* __restrict__ node_feats, const float* __restrict__ edge_feats,
    const int* __restrict__ src, const int* __restrict__ dst,
    const int* __restrict__ gids,
    float* __restrict__ pf, int* __restrict__ pi, int E)
{
    __shared__ float acc[NB * ACC_W];   // 160000 B
    __shared__ int   scnt[NB];          // 2000 B
    const int t = threadIdx.x;
    for (int i = t; i < NB * ACC_W; i += 1024) acc[i] = 0.f;
    for (int i = t; i < NB; i += 1024) scnt[i] = 0;
    __syncthreads();

    const int lane = t & 63;
    const int wid  = blockIdx.x * 16 + (t >> 6);
    const int nw   = gridDim.x * 16;
    const int nbatch = (E + 63) >> 6;
    const int q  = lane >> 4;
    const int jj = lane & 15;

    for (int b = wid; b < nbatch; b += nw) {
        const int e0 = b << 6;
        const int e  = e0 + lane;
        int s = 0, g = -1;
        if (e < E) { g = gids[dst[e]]; s = src[e]; }
        if (g >= 0) atomicAdd(&scnt[g], 1);

        // node part: lane j holds feature j; broadcast each edge's (s,g) scalar.
        #pragma unroll
        for (int i = 0; i < 64; ++i) {
            const int gi = __builtin_amdgcn_readlane(g, i);
            const int si = __builtin_amdgcn_readlane(s, i);
            if (gi >= 0) {
                const float v = node_feats[(size_t)si * NODE_IN + lane];
                atomicAdd(&acc[gi * ACC_W + lane], v);
            }
        }
        // edge part: 4 edges x 16 features per step.
        #pragma unroll
        for (int k = 0; k < 16; ++k) {
            const int eq = k * 4 + q;
            const int gq = __shfl(g, eq);
            if (gq >= 0) {
                const float v = edge_feats[(size_t)(e0 + eq) * EDGE_IN + jj];
                atomicAdd(&acc[gq * ACC_W + NODE_IN + jj], v);
            }
        }
    }
    __syncthreads();
    for (int i = t; i < NB * ACC_W; i += 1024)
        pf[(size_t)blockIdx.x * (NB * ACC_W) + i] = acc[i];
    for (int i = t; i < NB; i += 1024)
        pi[(size_t)blockIdx.x * NB + i] = scnt[i];
}

// ---------------- Kernel 2: reduce partials, tiny GEMMs, softmax -> x[:, :160]
__global__ __launch_bounds__(256) void mol_kernel(
    const float* __restrict__ pf, const int* __restrict__ pi, int nblk,
    const float* __restrict__ Wm, const float* __restrict__ bm,
    const float* __restrict__ We, const float* __restrict__ be,
    float* __restrict__ xbuf)
{
    const int g = blockIdx.x;
    const int t = threadIdx.x;
    __shared__ float acc[ACC_W];
    __shared__ float red[256];
    __shared__ int   ired[256];
    __shared__ float molrow[160];

    float s = 0.f;
    if (t < 240) {
        const int c = t % 80, seg = t / 80;
        for (int b = seg; b < nblk; b += 3)
            s += pf[(size_t)b * (NB * ACC_W) + g * ACC_W + c];
    }
    red[t] = s;
    int ci = 0;
    for (int b = t; b < nblk; b += 256) ci += pi[(size_t)b * NB + g];
    ired[t] = ci;
    __syncthreads();
    if (t < 80) acc[t] = red[t] + red[t + 80] + red[t + 160];
    for (int st = 128; st > 0; st >>= 1) {
        if (t < st) ired[t] += ired[t + st];
        __syncthreads();
    }
    const float cntf = (float)ired[0];

    if (t < 96) {
        float m2 = 0.f;
        for (int k = 0; k < NODE_IN; ++k) m2 = fmaf(acc[k], Wm[k * NODE_OUT + t], m2);
        molrow[t] = m2 + cntf * bm[t];
    } else if (t < 160) {
        const int j = t - 96;
        float m2 = 0.f;
        for (int k = 0; k < EDGE_IN; ++k) m2 = fmaf(acc[NODE_IN + k], We[k * EDGE_OUT + j], m2);
        molrow[t] = m2 + cntf * be[j];
    }
    __syncthreads();

    red[t] = (t < 160) ? molrow[t] : -1e30f;
    __syncthreads();
    for (int st = 128; st > 0; st >>= 1) {
        if (t < st) red[t] = fmaxf(red[t], red[t + st]);
        __syncthreads();
    }
    const float mx = red[0];
    __syncthreads();
    const float ev = (t < 160) ? expf(molrow[t] - mx) : 0.f;
    red[t] = ev;
    __syncthreads();
    for (int st = 128; st > 0; st >>= 1) {
        if (t < st) red[t] += red[t + st];
        __syncthreads();
    }
    if (t < 160) xbuf[(size_t)g * XDIM + t] = ev / red[0];
}

// ---------------- Kernel 3: fingerprint encoder -> x[:, 160:288] -------------
__global__ __launch_bounds__(256) void fp_kernel(
    const float* __restrict__ fpv, const float* __restrict__ Wf,
    const float* __restrict__ bf, const float* __restrict__ gam,
    const float* __restrict__ bet, const float* __restrict__ mu,
    const float* __restrict__ var, float* __restrict__ xbuf)
{
    __shared__ float xs[4 * FPD];   // 32 KB: 4 fingerprint rows
    const int t  = threadIdx.x;
    const int r0 = blockIdx.x * 4;
    for (int i = t; i < 4 * FPD; i += 256) xs[i] = fpv[(size_t)r0 * FPD + i];
    __syncthreads();

    const int j = t & 127, h = t >> 7;       // h in {0,1}: two rows each
    const float* xa = &xs[(2 * h) * FPD];
    const float* xb = &xs[(2 * h + 1) * FPD];
    float a0 = 0.f, a1 = 0.f;
    for (int k = 0; k < FPD; k += 4) {
        #pragma unroll
        for (int kk = 0; kk < 4; ++kk) {
            const float w = Wf[(size_t)(k + kk) * FPE + j];
            a0 = fmaf(xa[k + kk], w, a0);
            a1 = fmaf(xb[k + kk], w, a1);
        }
    }
    const float sc = rsqrtf(var[j] + BN_EPS) * gam[j];
    const float sh = bet[j] - mu[j] * sc;
    const float y0 = fmaxf(fmaf(a0 + bf[j], sc, sh), 0.f);
    const float y1 = fmaxf(fmaf(a1 + bf[j], sc, sh), 0.f);
    xbuf[(size_t)(r0 + 2 * h) * XDIM + 160 + j]     = y0;
    xbuf[(size_t)(r0 + 2 * h + 1) * XDIM + 160 + j] = y1;
}

// ---------------- Kernels 4-6: fp32 dense layers ------------------------------
__global__ __launch_bounds__(256) void ffn_kernel(
    const float* __restrict__ X, const float* __restrict__ W,
    const float* __restrict__ bias, float* __restrict__ Y,
    int Bv, int Ni, int No, int doRelu)
{
    __shared__ float xs[32][33];
    const int t = threadIdx.x;
    const int col = blockIdx.y * 64 + (t & 63);
    const int rg = t >> 6;                    // 0..3 row groups, 8 rows each
    const int rowBase = blockIdx.x * 32;
    float acc[8] = {0, 0, 0, 0, 0, 0, 0, 0};

    for (int kc = 0; kc < Ni; kc += 32) {
        for (int i = t; i < 32 * 32; i += 256) {
            const int r = i >> 5, k = i & 31;
            xs[r][k] = (rowBase + r < Bv) ? X[(size_t)(rowBase + r) * Ni + kc + k] : 0.f;
        }
        __syncthreads();
        for (int k = 0; k < 32; ++k) {
            const float w = W[(size_t)(kc + k) * No + col];
            #pragma unroll
            for (int rr = 0; rr < 8; ++rr)
                acc[rr] = fmaf(xs[rg * 8 + rr][k], w, acc[rr]);
        }
        __syncthreads();
    }
    const float bv = bias[col];
    #pragma unroll
    for (int rr = 0; rr < 8; ++rr) {
        const int r = rowBase + rg * 8 + rr;
        if (r < Bv) {
            float v = acc[rr] + bv;
            if (doRelu) v = fmaxf(v, 0.f);
            Y[(size_t)r * No + col] = v;
        }
    }
}

extern "C" void kernel_launch(void* const* d_in, const int* in_sizes, int n_in,
                              void* d_out, int out_size, void* d_ws, size_t ws_size,
                              hipStream_t stream)
{
    const float* node_feats = (const float*)d_in[0];
    const float* edge_feats = (const float*)d_in[1];
    const float* fpv        = (const float*)d_in[2];
    const int*   src        = (const int*)d_in[3];
    const int*   dst        = (const int*)d_in[4];
    const int*   gids       = (const int*)d_in[5];
    const float* Wm  = (const float*)d_in[6];
    const float* bm  = (const float*)d_in[7];
    const float* We  = (const float*)d_in[8];
    const float* be  = (const float*)d_in[9];
    const float* Wf  = (const float*)d_in[10];
    const float* bf  = (const float*)d_in[11];
    const float* gam = (const float*)d_in[12];
    const float* bet = (const float*)d_in[13];
    const float* mu  = (const float*)d_in[14];
    const float* var = (const float*)d_in[15];
    const float* W0  = (const float*)d_in[16];
    const float* b0  = (const float*)d_in[17];
    const float* W1  = (const float*)d_in[18];
    const float* b1  = (const float*)d_in[19];
    const float* W2  = (const float*)d_in[20];
    const float* b2  = (const float*)d_in[21];
    const int E = in_sizes[3];

    float* xbuf = (float*)d_ws;                       // [500][288]
    float* h1   = xbuf + (size_t)NB * XDIM;           // [500][512]
    float* h2   = h1 + (size_t)NB * 512;              // [500][512]
    float* pf   = h2 + (size_t)NB * 512;              // [nblk][500][80]
    const size_t fixed = ((size_t)NB * XDIM + (size_t)NB * 512 * 2) * 4;
    long long avail = (long long)ws_size - (long long)fixed;
    int nblk = (int)(avail / (long long)((NB * ACC_W + NB) * 4));
    if (nblk > 256) nblk = 256;
    if (nblk < 8) nblk = 8;
    int* pi = (int*)(pf + (size_t)nblk * NB * ACC_W);

    hipLaunchKernelGGL(edge_scatter, dim3(nblk), dim3(1024), 0, stream,
                       node_feats, edge_feats, src, dst, gids, pf, pi, E);
    hipLaunchKernelGGL(mol_kernel, dim3(NB), dim3(256), 0, stream,
                       pf, pi, nblk, Wm, bm, We, be, xbuf);
    hipLaunchKernelGGL(fp_kernel, dim3(NB / 4), dim3(256), 0, stream,
                       fpv, Wf, bf, gam, bet, mu, var, xbuf);
    hipLaunchKernelGGL(ffn_kernel, dim3((NB + 31) / 32, 512 / 64), dim3(256), 0, stream,
                       xbuf, W0, b0, h1, NB, XDIM, 512, 1);
    hipLaunchKernelGGL(ffn_kernel, dim3((NB + 31) / 32, 512 / 64), dim3(256), 0, stream,
                       h1, W1, b1, h2, NB, 512, 512, 1);
    hipLaunchKernelGGL(ffn_kernel, dim3((NB + 31) / 32, 256 / 64), dim3(256), 0, stream,
                       h2, W2, b2, (float*)d_out, NB, 512, 256, 0);
}